// Round 1
// baseline (570.205 us; speedup 1.0000x reference)
//
#include <hip/hip_runtime.h>

#define L    112
#define IMG  224
#define KS   7
#define CIN  3
#define COUT 64
#define BATCH 32
#define PAD  12
#define NPOS (BATCH * L * L)          // 401408
#define PLANE (L * L)                 // 12544
#define NTOT (NPOS * COUT)            // 25690112
#define EPS  1e-5f

// ---------------------------------------------------------------------------
// Pass 1: foveal gather + 147-tap conv into 64 channels per position.
// One thread = one (b,i,j); acc[64] lives in VGPRs (fully unrolled o-loop).
// Weights are wave-uniform -> scalar loads.
// ---------------------------------------------------------------------------
__global__ __launch_bounds__(256) void foveal_conv(
    const float* __restrict__ x, const float* __restrict__ w,
    const int* __restrict__ locs_i, const int* __restrict__ locs_j,
    float* __restrict__ out)
{
    const int pos = blockIdx.x * 256 + threadIdx.x;   // < NPOS (exact grid)
    const int b  = pos / PLANE;
    const int ij = pos - b * PLANE;

    // Gather lattice indices for this output position (shifted to x coords).
    int ri[KS], cc[KS];
#pragma unroll
    for (int q = 0; q < KS; ++q) ri[q] = locs_i[ij * KS + q] - PAD;
#pragma unroll
    for (int p = 0; p < KS; ++p) cc[p] = locs_j[ij * KS + p] - PAD;

    float acc[COUT];
#pragma unroll
    for (int o = 0; o < COUT; ++o) acc[o] = 0.f;

    for (int c = 0; c < CIN; ++c) {
        const float* xc = x + (size_t)(b * CIN + c) * (IMG * IMG);
        for (int q = 0; q < KS; ++q) {
            const int r = ri[q];
            const bool rin = (unsigned)r < (unsigned)IMG;
            const int rr = min(max(r, 0), IMG - 1);
            float g[KS];
#pragma unroll
            for (int p = 0; p < KS; ++p) {
                const int col = cc[p];
                const bool in = rin && ((unsigned)col < (unsigned)IMG);
                const int c2 = min(max(col, 0), IMG - 1);
                const float v = xc[rr * IMG + c2];
                g[p] = in ? v : 0.5f;   // reference pads with 0.5
            }
            // weight base for (c, q); per (o,p) offset is compile-time affine
            const float* wb = w + c * (KS * KS) + q;
#pragma unroll
            for (int o = 0; o < COUT; ++o) {
                float a = acc[o];
#pragma unroll
                for (int p = 0; p < KS; ++p)
                    a = fmaf(wb[o * (CIN * KS * KS) + p * KS], g[p], a);
                acc[o] = a;
            }
        }
    }

    float* op = out + (size_t)b * COUT * PLANE + ij;
#pragma unroll
    for (int o = 0; o < COUT; ++o)
        op[(size_t)o * PLANE] = acc[o];   // coalesced across lanes (j-contiguous)
}

// ---------------------------------------------------------------------------
// Pass 2a: per-channel sum / sumsq. One block per (b,o) plane.
// ws[0..63] = sum, ws[64..127] = sumsq (pre-zeroed by memset).
// ---------------------------------------------------------------------------
__global__ __launch_bounds__(256) void reduce_stats(
    const float* __restrict__ out, float* __restrict__ ws)
{
    const int plane = blockIdx.x;           // b*COUT + o
    const int o = plane & (COUT - 1);
    const float* p = out + (size_t)plane * PLANE;

    float s = 0.f, sq = 0.f;
    for (int t = threadIdx.x; t < PLANE; t += 256) {
        const float v = p[t];
        s += v;
        sq += v * v;
    }
#pragma unroll
    for (int off = 32; off > 0; off >>= 1) {
        s  += __shfl_down(s,  off);
        sq += __shfl_down(sq, off);
    }
    __shared__ float ls[4], lsq[4];
    const int wid = threadIdx.x >> 6;
    if ((threadIdx.x & 63) == 0) { ls[wid] = s; lsq[wid] = sq; }
    __syncthreads();
    if (threadIdx.x == 0) {
        s  = ls[0] + ls[1] + ls[2] + ls[3];
        sq = lsq[0] + lsq[1] + lsq[2] + lsq[3];
        atomicAdd(&ws[o], s);
        atomicAdd(&ws[COUT + o], sq);
    }
}

// ---------------------------------------------------------------------------
// Pass 2b: fold sums into per-channel scale/shift.
// ws[128..191] = scale, ws[192..255] = shift.
// ---------------------------------------------------------------------------
__global__ __launch_bounds__(64) void fold_stats(
    float* __restrict__ ws, const float* __restrict__ gamma,
    const float* __restrict__ beta)
{
    const int o = threadIdx.x;
    const float n = (float)NPOS;
    const float mean = ws[o] / n;
    float var = ws[COUT + o] / n - mean * mean;
    var = fmaxf(var, 0.f);
    const float sc = gamma[o] * rsqrtf(var + EPS);
    ws[2 * COUT + o] = sc;
    ws[3 * COUT + o] = beta[o] - mean * sc;
}

// ---------------------------------------------------------------------------
// Pass 3: y = relu(conv * scale[o] + shift[o]), in place, float4.
// ---------------------------------------------------------------------------
__global__ __launch_bounds__(256) void norm_relu(
    float4* __restrict__ out, const float* __restrict__ ws)
{
    const int idx = blockIdx.x * 256 + threadIdx.x;   // < NTOT/4 (exact grid)
    const int o = (idx / (PLANE / 4)) & (COUT - 1);
    const float sc = ws[2 * COUT + o];
    const float sh = ws[3 * COUT + o];
    float4 v = out[idx];
    v.x = fmaxf(fmaf(v.x, sc, sh), 0.f);
    v.y = fmaxf(fmaf(v.y, sc, sh), 0.f);
    v.z = fmaxf(fmaf(v.z, sc, sh), 0.f);
    v.w = fmaxf(fmaf(v.w, sc, sh), 0.f);
    out[idx] = v;
}

// ---------------------------------------------------------------------------
extern "C" void kernel_launch(void* const* d_in, const int* in_sizes, int n_in,
                              void* d_out, int out_size, void* d_ws, size_t ws_size,
                              hipStream_t stream)
{
    const float* x      = (const float*)d_in[0];
    const float* conv_w = (const float*)d_in[1];
    const float* gamma  = (const float*)d_in[2];
    const float* beta   = (const float*)d_in[3];
    const int*   locs_i = (const int*)d_in[4];
    const int*   locs_j = (const int*)d_in[5];
    float* out = (float*)d_out;
    float* ws  = (float*)d_ws;

    // zero the 256-float stats area every launch (graph-capture safe)
    hipMemsetAsync(d_ws, 0, 4 * COUT * sizeof(float), stream);

    foveal_conv<<<NPOS / 256, 256, 0, stream>>>(x, conv_w, locs_i, locs_j, out);
    reduce_stats<<<BATCH * COUT, 256, 0, stream>>>(out, ws);
    fold_stats<<<1, 64, 0, stream>>>(ws, gamma, beta);
    norm_relu<<<NTOT / 4 / 256, 256, 0, stream>>>((float4*)out, ws);
}

// Round 2
// 196.283 us; speedup vs baseline: 2.9050x; 2.9050x over previous
//
#include <hip/hip_runtime.h>
#include <hip/hip_bf16.h>

#define L    112
#define IMG  224
#define KS   7
#define CIN  3
#define COUT 64
#define BATCH 32
#define PAD  12
#define NPOS (BATCH * L * L)          // 401408
#define PLANE (L * L)                 // 12544
#define NTOT (NPOS * COUT)            // 25690112
#define EPS  1e-5f
#define KPAD 160                      // 147 rounded up to 32

typedef short bf16x8 __attribute__((ext_vector_type(8)));
typedef float f32x4  __attribute__((ext_vector_type(4)));

__device__ __forceinline__ short f2bf(float v) {
    __hip_bfloat16 h = __float2bfloat16(v);   // RNE
    return *reinterpret_cast<short*>(&h);
}

// ---------------------------------------------------------------------------
// Prep: Wt[o][k] (bf16, k-contiguous) with k = c*49 + q*7 + p mapping to
// weight w[o][c][p][q]  (NOTE p/q roles verified by round-0 fp32 kernel).
// k in [147,160) -> 0.
// ---------------------------------------------------------------------------
__global__ __launch_bounds__(256) void prep_weights(
    const float* __restrict__ w, unsigned short* __restrict__ wt)
{
    const int idx = blockIdx.x * 256 + threadIdx.x;   // < COUT*KPAD = 10240
    const int o = idx / KPAD;
    const int k = idx - o * KPAD;
    float v = 0.f;
    if (k < CIN * KS * KS) {
        const int c = (k >= 98) ? 2 : (k >= 49 ? 1 : 0);
        const int r = k - c * 49;
        const int q = (r * 37) >> 8;          // floor(r/7) for r<49
        const int p = r - q * 7;
        v = w[o * (CIN * KS * KS) + c * (KS * KS) + p * KS + q];
    }
    wt[idx] = (unsigned short)f2bf(v);
}

// ---------------------------------------------------------------------------
// Conv via MFMA. One wave = 16 consecutive positions x 64 channels.
// A = Wt (channels x K), B = gathered pixels (K x positions).
// A-frag lane l: row = l&15 (channel), k = 8*(l>>4)+e   -> b128 load from Wt
// B-frag lane l: col = l&15 (position), k = 8*(l>>4)+e  -> per-lane gather
// C/D lane l: col = l&15 (position), row = (l>>4)*4+reg (channel) [verified]
// ---------------------------------------------------------------------------
__global__ __launch_bounds__(256) void foveal_conv_mfma(
    const float* __restrict__ x, const unsigned short* __restrict__ wt,
    const int* __restrict__ locs_i, const int* __restrict__ locs_j,
    float* __restrict__ out)
{
    const int lane = threadIdx.x & 63;
    const int wid  = threadIdx.x >> 6;
    const int tile = blockIdx.x * 4 + wid;        // 25088 tiles of 16 positions
    const int posbase = tile * 16;
    const int b = posbase / PLANE;                // PLANE % 16 == 0: no b-crossing
    const int ijbase = posbase - b * PLANE;
    const int col = lane & 15;
    const int kb  = (lane >> 4) * 8;

    // lattice rows/cols for this lane's position
    const int ij = ijbase + col;
    int ri[KS], cc[KS];
#pragma unroll
    for (int q = 0; q < KS; ++q) ri[q] = locs_i[ij * KS + q] - PAD;
#pragma unroll
    for (int p = 0; p < KS; ++p) cc[p] = locs_j[ij * KS + p] - PAD;

    // gather B fragments: k = ks*32 + kb + e, value = x[b,c,ri[q],cc[p]]
    const float* xb = x + (size_t)b * (CIN * IMG * IMG);
    bf16x8 bfrag[5];
#pragma unroll
    for (int ks = 0; ks < 5; ++ks) {
#pragma unroll
        for (int e = 0; e < 8; ++e) {
            const int k = ks * 32 + kb + e;
            float v = 0.f;
            if (k < CIN * KS * KS) {
                const int c = (k >= 98) ? 2 : (k >= 49 ? 1 : 0);
                const int r = k - c * 49;
                const int q = (r * 37) >> 8;
                const int p = r - q * 7;
                const int row = ri[q], ccol = cc[p];
                const bool in = ((unsigned)row < (unsigned)IMG) &&
                                ((unsigned)ccol < (unsigned)IMG);
                const int r2 = min(max(row, 0), IMG - 1);
                const int c2 = min(max(ccol, 0), IMG - 1);
                const float xv = xb[c * (IMG * IMG) + r2 * IMG + c2];
                v = in ? xv : 0.5f;               // reference pads with 0.5
            }
            bfrag[ks][e] = f2bf(v);
        }
    }

    // A fragments: 4 channel-tiles x 5 k-steps, 16B loads (L2-resident)
    bf16x8 afrag[4][5];
#pragma unroll
    for (int ct = 0; ct < 4; ++ct)
#pragma unroll
        for (int ks = 0; ks < 5; ++ks)
            afrag[ct][ks] = *reinterpret_cast<const bf16x8*>(
                wt + (ct * 16 + col) * KPAD + ks * 32 + kb);

    f32x4 acc[4];
#pragma unroll
    for (int ct = 0; ct < 4; ++ct) acc[ct] = (f32x4){0.f, 0.f, 0.f, 0.f};

#pragma unroll
    for (int ks = 0; ks < 5; ++ks)
#pragma unroll
        for (int ct = 0; ct < 4; ++ct)
            acc[ct] = __builtin_amdgcn_mfma_f32_16x16x32_bf16(
                afrag[ct][ks], bfrag[ks], acc[ct], 0, 0, 0);

    // store: lanes 0..15 write 16 consecutive ij for one channel -> coalesced
#pragma unroll
    for (int ct = 0; ct < 4; ++ct) {
#pragma unroll
        for (int r = 0; r < 4; ++r) {
            const int ch = ct * 16 + (lane >> 4) * 4 + r;
            out[((size_t)b * COUT + ch) * PLANE + ijbase + col] = acc[ct][r];
        }
    }
}

// ---------------------------------------------------------------------------
// Pass 2a: per-channel sum / sumsq. One block per (b,o) plane.
// ---------------------------------------------------------------------------
__global__ __launch_bounds__(256) void reduce_stats(
    const float* __restrict__ out, float* __restrict__ ws)
{
    const int plane = blockIdx.x;           // b*COUT + o
    const int o = plane & (COUT - 1);
    const float* p = out + (size_t)plane * PLANE;

    float s = 0.f, sq = 0.f;
    for (int t = threadIdx.x; t < PLANE; t += 256) {
        const float v = p[t];
        s += v;
        sq += v * v;
    }
#pragma unroll
    for (int off = 32; off > 0; off >>= 1) {
        s  += __shfl_down(s,  off);
        sq += __shfl_down(sq, off);
    }
    __shared__ float ls[4], lsq[4];
    const int wid = threadIdx.x >> 6;
    if ((threadIdx.x & 63) == 0) { ls[wid] = s; lsq[wid] = sq; }
    __syncthreads();
    if (threadIdx.x == 0) {
        s  = ls[0] + ls[1] + ls[2] + ls[3];
        sq = lsq[0] + lsq[1] + lsq[2] + lsq[3];
        atomicAdd(&ws[o], s);
        atomicAdd(&ws[COUT + o], sq);
    }
}

__global__ __launch_bounds__(64) void fold_stats(
    float* __restrict__ ws, const float* __restrict__ gamma,
    const float* __restrict__ beta)
{
    const int o = threadIdx.x;
    const float n = (float)NPOS;
    const float mean = ws[o] / n;
    float var = ws[COUT + o] / n - mean * mean;
    var = fmaxf(var, 0.f);
    const float sc = gamma[o] * rsqrtf(var + EPS);
    ws[2 * COUT + o] = sc;
    ws[3 * COUT + o] = beta[o] - mean * sc;
}

__global__ __launch_bounds__(256) void norm_relu(
    float4* __restrict__ out, const float* __restrict__ ws)
{
    const int idx = blockIdx.x * 256 + threadIdx.x;   // < NTOT/4 (exact grid)
    const int o = (idx / (PLANE / 4)) & (COUT - 1);
    const float sc = ws[2 * COUT + o];
    const float sh = ws[3 * COUT + o];
    float4 v = out[idx];
    v.x = fmaxf(fmaf(v.x, sc, sh), 0.f);
    v.y = fmaxf(fmaf(v.y, sc, sh), 0.f);
    v.z = fmaxf(fmaf(v.z, sc, sh), 0.f);
    v.w = fmaxf(fmaf(v.w, sc, sh), 0.f);
    out[idx] = v;
}

// ---------------------------------------------------------------------------
extern "C" void kernel_launch(void* const* d_in, const int* in_sizes, int n_in,
                              void* d_out, int out_size, void* d_ws, size_t ws_size,
                              hipStream_t stream)
{
    const float* x      = (const float*)d_in[0];
    const float* conv_w = (const float*)d_in[1];
    const float* gamma  = (const float*)d_in[2];
    const float* beta   = (const float*)d_in[3];
    const int*   locs_i = (const int*)d_in[4];
    const int*   locs_j = (const int*)d_in[5];
    float* out = (float*)d_out;
    float* ws  = (float*)d_ws;
    unsigned short* wt = (unsigned short*)((char*)d_ws + 1024);  // Wt[64][160] bf16

    hipMemsetAsync(d_ws, 0, 1024, stream);  // zero stats area

    prep_weights<<<(COUT * KPAD) / 256, 256, 0, stream>>>(conv_w, wt);
    foveal_conv_mfma<<<NPOS / 64, 256, 0, stream>>>(x, wt, locs_i, locs_j, out);
    reduce_stats<<<BATCH * COUT, 256, 0, stream>>>(out, ws);
    fold_stats<<<1, 64, 0, stream>>>(ws, gamma, beta);
    norm_relu<<<NTOT / 4 / 256, 256, 0, stream>>>((float4*)out, ws);
}